// Round 8
// baseline (837.259 us; speedup 1.0000x reference)
//
#include <hip/hip_runtime.h>
#include <cstdint>
#include <cstddef>

// Problem constants
#define LSEQ 2048
#define BB   32
#define DD   1024
#define NLAYERS 4
#define MM   (LSEQ*BB)      // 65536 rows
#define BD   (BB*DD)        // 32768
#define CHUNK 32
#define NCHUNK (LSEQ/CHUNK) // 64

typedef _Float16 f16;
typedef __attribute__((ext_vector_type(8))) _Float16 f16x8;
typedef __attribute__((ext_vector_type(4))) float f32x4;

// ---------------- scan: h[t] = a*h[t-1] + x[t], a = exp(A_log[d]) ----------------

__global__ void scan_pass1(const float* __restrict__ x, const float* __restrict__ Alog,
                           f16* __restrict__ h, float* __restrict__ carry) {
    int tid = blockIdx.x * blockDim.x + threadIdx.x;   // 2M threads
    int bd  = tid & (BD - 1);
    int c   = tid >> 15;                               // chunk id
    float a = expf(Alog[bd & (DD - 1)]);
    size_t base = (size_t)c * CHUNK * BD + bd;
    float hv = 0.f;
#pragma unroll
    for (int i = 0; i < CHUNK; ++i) {
        hv = a * hv + x[base + (size_t)i * BD];
        h[base + (size_t)i * BD] = (f16)hv;
    }
    carry[c * BD + bd] = hv;
}

__global__ void scan_pass2(const float* __restrict__ Alog, float* __restrict__ carry) {
    int bd = blockIdx.x * blockDim.x + threadIdx.x;    // 32768 threads
    float d32 = expf((float)CHUNK * Alog[bd & (DD - 1)]);  // a^CHUNK
    float cin = 0.f;
    for (int c = 0; c < NCHUNK; ++c) {
        float co = carry[c * BD + bd];
        carry[c * BD + bd] = cin;       // exclusive carry-in
        cin = d32 * cin + co;
    }
}

__global__ void scan_pass3(const float* __restrict__ Alog, const float* __restrict__ carry,
                           f16* __restrict__ h) {
    int tid = blockIdx.x * blockDim.x + threadIdx.x;
    int bd  = tid & (BD - 1);
    int c   = tid >> 15;
    float a   = expf(Alog[bd & (DD - 1)]);
    float cin = carry[c * BD + bd];
    size_t base = (size_t)c * CHUNK * BD + bd;
    float p = a;
#pragma unroll
    for (int i = 0; i < CHUNK; ++i) {
        size_t idx = base + (size_t)i * BD;
        float hv = (float)h[idx] + p * cin;
        h[idx] = (f16)hv;
        p *= a;
    }
}

// ---------------- fp32 -> fp16 weight conversion ----------------

__global__ void cvt_w(const float* __restrict__ w, f16* __restrict__ o, int n) {
    int i = (blockIdx.x * blockDim.x + threadIdx.x) * 4;
    if (i + 3 < n) {
        float4 v = *(const float4*)&w[i];
        o[i + 0] = (f16)v.x; o[i + 1] = (f16)v.y;
        o[i + 2] = (f16)v.z; o[i + 3] = (f16)v.w;
    }
}

// ---------------- GEMM + bias + tanh: 3-buffer ring, 1 barrier/K-tile ----------------
// C[m][n] = tanh(sum_k A[m][k]*W[n][k] + b[n])
// Tile 256x256, BK=32, 32 K-tiles, LDS ring of 3 buffers (96 KiB total).
// 512 thr = 8 waves (2Mx4N), wave tile 128x64, mfma 16x16x32 f16, acc 8x4.
// Per phase t:  stage(t+2 -> ring[(t+2)%3])   [issued FIRST: ~2 phases to land]
//               12 ds_read (ring[t%3]) -> 32 MFMA (compiler inserts counted lgkm)
//               vmcnt(4)  [t+1's 4 loads landed; t+2's 4 still in flight]
//               s_barrier [publishes ring[(t+1)%3]; frees ring[t%3] for t+1's stage]
// NO lgkmcnt(0) drain anywhere: a wave's 32 MFMAs consume all 12 of its reads,
// so reads are retired before the wave reaches the barrier; the barrier then
// proves ring[t%3] is fully read block-wide before its overwrite at t+1.
// vmcnt(0) only at t=30 (last staged tile). Stores appear only in epilogue,
// so vmcnt counts exactly the gload_lds queue.
// T2 swizzle for 64B rows: chunk ^= (row>>1)&3  (2-way residual = free);
// inverse-swizzled global source, linear gload_lds dest (rule #21).
// T5: setprio around MFMA cluster. T1: XCD-chunked block swizzle.

#define BM 256
#define BN 256
#define BK 32
#define KK 1024
#define NN 1024
#define NKT (KK / BK)        // 32 K-tiles

__device__ __forceinline__ void gload_lds16(const void* g, void* l) {
    __builtin_amdgcn_global_load_lds((const __attribute__((address_space(1))) unsigned int*)g,
                                     (__attribute__((address_space(3))) unsigned int*)l,
                                     16, 0, 0);
}

// stage one K-tile (A 256x32 + W 256x32 = 32 KiB): 4 loads/thread.
// slot s (16B): row r = s>>2 (0..255), chunk c = (s&3) ^ ((r>>1)&3)  [inverse swz]
__device__ __forceinline__ void stage_kt(const f16* __restrict__ gA, const f16* __restrict__ gW,
                                         f16* As_, f16* Bs_, int tid) {
#pragma unroll
    for (int j = 0; j < 2; ++j) {
        int s = tid + j * 512;
        int r = s >> 2;
        int c = (s & 3) ^ ((r >> 1) & 3);
        gload_lds16(gA + (size_t)r * KK + c * 8, As_ + (size_t)s * 8);
    }
#pragma unroll
    for (int j = 0; j < 2; ++j) {
        int s = tid + j * 512;
        int r = s >> 2;
        int c = (s & 3) ^ ((r >> 1) & 3);
        gload_lds16(gW + (size_t)r * KK + c * 8, Bs_ + (size_t)s * 8);
    }
}

// swizzled fragment read from a [256][32] f16 tile
__device__ __forceinline__ f16x8 rd(const f16* base, int row, int chunk) {
    int c = chunk ^ ((row >> 1) & 3);
    return *(const f16x8*)(base + row * 32 + c * 8);
}

__device__ __forceinline__ float tanh_fast(float z) {
    float e = __expf(2.f * z);
    return 1.f - 2.f / (e + 1.f);
}

#define BAR() do { __builtin_amdgcn_sched_barrier(0); __builtin_amdgcn_s_barrier(); \
                   __builtin_amdgcn_sched_barrier(0); } while (0)

__global__ __launch_bounds__(512, 2) void gemm_tanh(const f16* __restrict__ A,
                                                    const f16* __restrict__ W,
                                                    const float* __restrict__ bias,
                                                    f16* __restrict__ C) {
    __shared__ f16 As[3][BM * BK];   // 3 x 16 KiB
    __shared__ f16 Bs[3][BN * BK];   // 3 x 16 KiB

    const int tid  = threadIdx.x;
    const int lane = tid & 63;
    const int wid  = tid >> 6;        // 0..7
    const int wr   = wid >> 2;        // 0..1  (M half)
    const int wc   = wid & 3;         // 0..3  (N quarter)

    // T1: XCD-chunked bijective swizzle (nwg=1024, %8==0)
    const int cpx = gridDim.x >> 3;
    const int lin = ((int)blockIdx.x & 7) * cpx + ((int)blockIdx.x >> 3);
    const int tm  = (lin >> 2) * BM;
    const int tn  = (lin & 3) * BN;

    const f16* Ab = A + (size_t)tm * KK;
    const f16* Wb = W + (size_t)tn * KK;

    const int fr = lane & 15;         // fragment row within 16
    const int fc = lane >> 4;         // 16B k-chunk 0..3 (k = fc*8..fc*8+7)

    f32x4 acc[8][4];
#pragma unroll
    for (int i = 0; i < 8; ++i)
#pragma unroll
        for (int j = 0; j < 4; ++j)
            acc[i][j] = (f32x4){0.f, 0.f, 0.f, 0.f};

    // prologue: tiles 0,1 -> ring[0],ring[1]; wait tile0; publish
    stage_kt(Ab,      Wb,      &As[0][0], &Bs[0][0], tid);
    stage_kt(Ab + BK, Wb + BK, &As[1][0], &Bs[1][0], tid);
    asm volatile("s_waitcnt vmcnt(4)" ::: "memory");   // tile0 landed
    BAR();

    const int arow = wr * 128 + fr;
    const int brow = wc * 64  + fr;

#pragma unroll
    for (int t = 0; t < NKT; ++t) {
        const f16* Ac = &As[t % 3][0];
        const f16* Bc = &Bs[t % 3][0];

        // issue next-next tile's loads first (land ~2 phases later)
        if (t + 2 < NKT)
            stage_kt(Ab + (size_t)(t + 2) * BK, Wb + (size_t)(t + 2) * BK,
                     &As[(t + 2) % 3][0], &Bs[(t + 2) % 3][0], tid);

        // 12 fragment reads + 32 MFMA (compiler pipelines with counted lgkm)
        f16x8 a[8], b[4];
#pragma unroll
        for (int m = 0; m < 8; ++m) a[m] = rd(Ac, arow + m * 16, fc);
#pragma unroll
        for (int n = 0; n < 4; ++n) b[n] = rd(Bc, brow + n * 16, fc);
        __builtin_amdgcn_s_setprio(1);
#pragma unroll
        for (int m = 0; m < 8; ++m)
#pragma unroll
            for (int n = 0; n < 4; ++n)
                acc[m][n] = __builtin_amdgcn_mfma_f32_16x16x32_f16(a[m], b[n], acc[m][n], 0, 0, 0);
        __builtin_amdgcn_s_setprio(0);

        // counted drain: t+1's 4 loads landed (t+2's 4 stay in flight)
        if (t + 2 < NKT)      asm volatile("s_waitcnt vmcnt(4)" ::: "memory");
        else if (t + 2 == NKT) asm volatile("s_waitcnt vmcnt(0)" ::: "memory");
        if (t + 1 < NKT) BAR();   // publish ring[(t+1)%3], free ring[t%3]
    }

    // epilogue: bias + fast tanh, store f16 (mi outer: row-major store order)
#pragma unroll
    for (int mi = 0; mi < 8; ++mi) {
        const int r0 = tm + wr * 128 + mi * 16 + (fc << 2);
#pragma unroll
        for (int ni = 0; ni < 4; ++ni) {
            const int c = tn + wc * 64 + ni * 16 + fr;
            const float bv = bias[c];
#pragma unroll
            for (int q = 0; q < 4; ++q) {
                float z = acc[mi][ni][q] + bv;
                C[(size_t)(r0 + q) * NN + c] = (f16)tanh_fast(z);
            }
        }
    }
}

// ---------------- head: out[m] = sum_d h[m][d]*hw[d] + hb ----------------

__global__ void head_k(const f16* __restrict__ h, const float* __restrict__ hw,
                       const float* __restrict__ hb, float* __restrict__ out) {
    const int row  = blockIdx.x * 4 + (threadIdx.x >> 6);
    const int lane = threadIdx.x & 63;
    const f16* hr = h + (size_t)row * DD;
    float s = 0.f;
#pragma unroll
    for (int j = 0; j < DD / 64; ++j) {
        int d = lane + j * 64;
        s += (float)hr[d] * hw[d];
    }
#pragma unroll
    for (int o = 32; o > 0; o >>= 1) s += __shfl_down(s, o, 64);
    if (lane == 0) out[row] = s + hb[0];
}

// ---------------- launch ----------------

extern "C" void kernel_launch(void* const* d_in, const int* in_sizes, int n_in,
                              void* d_out, int out_size, void* d_ws, size_t ws_size,
                              hipStream_t stream) {
    const float* x    = (const float*)d_in[0];
    const float* Alog = (const float*)d_in[1];
    const float* Wls  = (const float*)d_in[2];
    const float* bls  = (const float*)d_in[3];
    const float* hw   = (const float*)d_in[4];
    const float* hb   = (const float*)d_in[5];
    float* out = (float*)d_out;

    char* ws = (char*)d_ws;
    const size_t hbytes = (size_t)MM * DD * sizeof(f16);   // 128 MiB
    f16* h0 = (f16*)ws;
    f16* h1 = (f16*)(ws + hbytes);
    char* scratch = ws + 2 * hbytes;
    float* carry = (float*)scratch;                         // 8 MiB, scan phase only
    f16*   wf    = (f16*)scratch;                           // 8 MiB, reused after scan

    // 1. scan (chunked, 3 passes)
    scan_pass1<<<(NCHUNK * BD) / 256, 256, 0, stream>>>(x, Alog, h0, carry);
    scan_pass2<<<BD / 256, 256, 0, stream>>>(Alog, carry);
    scan_pass3<<<(NCHUNK * BD) / 256, 256, 0, stream>>>(Alog, carry, h0);

    // 2. weights fp32 -> fp16 (reuses carry region; stream-ordered after pass3)
    cvt_w<<<(NLAYERS * DD * DD / 4) / 256, 256, 0, stream>>>(Wls, wf, NLAYERS * DD * DD);

    // 3. four layers, ping-pong (1-D grid of 1024 blocks, swizzles inside kernel)
    dim3 grid((MM / BM) * (NN / BN)), blk(512);
    gemm_tanh<<<grid, blk, 0, stream>>>(h0, wf + 0 * (DD * DD), bls + 0 * DD, h1);
    gemm_tanh<<<grid, blk, 0, stream>>>(h1, wf + 1 * (DD * DD), bls + 1 * DD, h0);
    gemm_tanh<<<grid, blk, 0, stream>>>(h0, wf + 2 * (DD * DD), bls + 2 * DD, h1);
    gemm_tanh<<<grid, blk, 0, stream>>>(h1, wf + 3 * (DD * DD), bls + 3 * DD, h0);

    // 4. head
    head_k<<<MM / 4, 256, 0, stream>>>(h0, hw, hb, out);
}